// Round 16
// baseline (318.914 us; speedup 1.0000x reference)
//
#include <hip/hip_runtime.h>

#define NN 60000
#define EE 1200000
#define NBK 938          // ceil(60000/64) buckets of 64 nodes
#define CH  4096         // edges per block-chunk in k_binsort

typedef __attribute__((ext_vector_type(8))) short short8;
typedef __attribute__((ext_vector_type(4))) float f32x4;

__device__ __forceinline__ float leakyf(float x){ return x >= 0.f ? x : 0.2f*x; }
__device__ __forceinline__ float eluf(float x){ return x > 0.f ? x : expm1f(x); }

__device__ __forceinline__ float bflo(uint v){ union{uint i;float f;}c; c.i = v<<16; return c.f; }
__device__ __forceinline__ float bfhi(uint v){ union{uint i;float f;}c; c.i = v & 0xffff0000u; return c.f; }
__device__ __forceinline__ ushort f2bf(float f){ union{float f;uint i;}c; c.f=f;
    uint r = c.i + 0x7fffu + ((c.i>>16)&1u); return (ushort)(r>>16); }
__device__ __forceinline__ uint pack2(float a, float b){ return (uint)f2bf(a) | ((uint)f2bf(b)<<16); }
__device__ __forceinline__ short8 ld8(const uint* p){
    union{ uint4 u; short8 s; } c; c.u = *(const uint4*)p; return c.s; }

// ---- bucket histogram (938 counters, LDS-aggregated) ----
__global__ __launch_bounds__(256) void k_bcount(const int* __restrict__ dst,
                                                int* __restrict__ bhist){
    __shared__ int lh[NBK];
    int t = threadIdx.x;
    for (int j = t; j < NBK; j += 256) lh[j] = 0;
    __syncthreads();
    for (int e = blockIdx.x*256 + t; e < EE; e += gridDim.x*256)
        atomicAdd(&lh[dst[e] >> 6], 1);
    __syncthreads();
    for (int j = t; j < NBK; j += 256){
        int v = lh[j];
        if (v) atomicAdd(&bhist[j], v);
    }
}

// ---- block 0: scan bhist -> bstart/bcur ; blocks 1..64: weight prep ----
__global__ __launch_bounds__(256) void k_prep(const int* __restrict__ bhist,
        int* __restrict__ bstart, int* __restrict__ bcur,
        const float* __restrict__ wl, const float* __restrict__ wr,
        const float* __restrict__ gcw,
        ushort* __restrict__ wcat, ushort* __restrict__ gcb){
    int blk = blockIdx.x, t = threadIdx.x;
    if (blk == 0){
        __shared__ int stmp[256];
        int vals[4], s4 = 0;
        #pragma unroll
        for (int k = 0; k < 4; k++){
            int idx = t*4 + k;
            vals[k] = (idx < NBK) ? bhist[idx] : 0;
            s4 += vals[k];
        }
        stmp[t] = s4; __syncthreads();
        for (int off = 1; off < 256; off <<= 1){
            int o = (t >= off) ? stmp[t-off] : 0;
            __syncthreads();
            stmp[t] += o;
            __syncthreads();
        }
        int ex = stmp[t] - s4;
        #pragma unroll
        for (int k = 0; k < 4; k++){
            int idx = t*4 + k;
            if (idx < NBK){ bstart[idx] = ex; bcur[idx] = ex; ex += vals[k]; }
        }
        if (t == 0) bstart[NBK] = EE;
    } else {
        int g = (blk-1)*256 + t;
        if (g < 16384){
            int o = g >> 8, k = g & 255;
            float v = (k < 128) ? wl[o*128 + k] : wr[o*128 + (k-128)];
            wcat[g] = f2bf(v);
        }
        if (g < 2048) gcb[g] = f2bf(gcw[g]);
    }
}

// ---- bucket-sort edges into packed pairs[] ((src<<6)|dstlocal) ----
__global__ __launch_bounds__(256) void k_binsort(const int* __restrict__ src,
        const int* __restrict__ dst, int* __restrict__ bcur,
        int* __restrict__ pairs){
    __shared__ int hist[NBK];
    __shared__ int loff[NBK];
    __shared__ int rcur[NBK];
    __shared__ int gbase[NBK];
    __shared__ int2 buf2[CH];
    __shared__ int stmp[256];
    int t = threadIdx.x;
    for (int e0 = blockIdx.x*CH; e0 < EE; e0 += gridDim.x*CH){
        int cnt = min(CH, EE - e0);
        for (int j = t; j < NBK; j += 256){ hist[j] = 0; rcur[j] = 0; }
        __syncthreads();
        int pk[16], bb[16];
        #pragma unroll
        for (int k = 0; k < 16; k++){
            int j = t + k*256;
            bool ok = j < cnt;
            int s = 0, d = 0;
            if (ok){ s = src[e0+j]; d = dst[e0+j]; atomicAdd(&hist[d >> 6], 1); }
            pk[k] = (s << 6) | (d & 63);
            bb[k] = ok ? (d >> 6) : -1;
        }
        __syncthreads();
        int b0 = t*4, ssum = 0, hv[4];
        #pragma unroll
        for (int k2 = 0; k2 < 4; k2++){
            int idx = b0 + k2;
            hv[k2] = (idx < NBK) ? hist[idx] : 0;
            ssum += hv[k2];
        }
        stmp[t] = ssum; __syncthreads();
        for (int off = 1; off < 256; off <<= 1){
            int o = (t >= off) ? stmp[t-off] : 0;
            __syncthreads();
            stmp[t] += o;
            __syncthreads();
        }
        int excl = stmp[t] - ssum;
        #pragma unroll
        for (int k2 = 0; k2 < 4; k2++){
            int idx = b0 + k2;
            if (idx < NBK){ loff[idx] = excl; excl += hv[k2]; }
        }
        __syncthreads();
        for (int j = t; j < NBK; j += 256){
            int h = hist[j];
            if (h) gbase[j] = atomicAdd(&bcur[j], h);
        }
        __syncthreads();
        #pragma unroll
        for (int k = 0; k < 16; k++){
            int b = bb[k];
            if (b >= 0){
                int lpos = loff[b] + atomicAdd(&rcur[b], 1);
                buf2[lpos] = make_int2(pk[k], b);
            }
        }
        __syncthreads();
        for (int j = t; j < cnt; j += 256){
            int2 pr = buf2[j];
            pairs[gbase[pr.y] + (j - loff[pr.y])] = pr.x;
        }
        __syncthreads();
    }
}

// ---- local CSR finalize: counts+scan+rp+dinv+col ----
__global__ __launch_bounds__(256) void k_csr_local(const int* __restrict__ bstart,
        const int* __restrict__ pairs, int* __restrict__ rp,
        int* __restrict__ col, float* __restrict__ dinv){
    __shared__ int cnt64[64];
    int b = blockIdx.x, t = threadIdx.x;
    int nb0 = b*64;
    int base = bstart[b];
    int bsz = bstart[b+1] - base;
    if (t < 64) cnt64[t] = 0;
    __syncthreads();
    for (int i = t; i < bsz; i += 256)
        atomicAdd(&cnt64[pairs[base+i] & 63], 1);
    __syncthreads();
    if (t < 64){
        int v = cnt64[t];
        int inc = v;
        #pragma unroll
        for (int d = 1; d < 64; d <<= 1){
            int o = __shfl_up(inc, d);
            if (t >= d) inc += o;
        }
        int ex = inc - v;
        int node = nb0 + t;
        if (node < NN){
            rp[node] = base + ex;
            dinv[node] = rsqrtf((float)(v + 1));
        }
        cnt64[t] = ex;
    }
    __syncthreads();
    for (int i = t; i < bsz; i += 256){
        int pv = pairs[base + i];
        int lpos = atomicAdd(&cnt64[pv & 63], 1);
        col[base + lpos] = pv >> 6;
    }
    if (b == 0 && t == 0) rp[NN] = EE;
}

// ---- GAT linear via MFMA ----
#define XTILE 938
__global__ __launch_bounds__(256) void k_xw_mfma(const float* __restrict__ x,
        const float* __restrict__ w, const float* __restrict__ att_s,
        const float* __restrict__ att_d, ushort* __restrict__ xw_h,
        float* __restrict__ a_src, float* __restrict__ a_dst){
    int t = threadIdx.x;
    int wv = t >> 6, lane = t & 63;
    int l15 = lane & 15, g = lane >> 4;
    short8 bw[2][2];
    float attv_s[2], attv_d[2];
    #pragma unroll
    for (int ct = 0; ct < 2; ct++){
        int colo = wv*32 + ct*16 + l15;
        attv_s[ct] = att_s[colo];
        attv_d[ct] = att_d[colo];
        #pragma unroll
        for (int ks = 0; ks < 2; ks++){
            const float* wp = w + colo*64 + ks*32 + g*8;
            short8 b;
            #pragma unroll
            for (int j = 0; j < 8; j++) b[j] = (short)f2bf(wp[j]);
            bw[ct][ks] = b;
        }
    }
    for (int tile = blockIdx.x; tile < XTILE; tile += gridDim.x){
        int nb = tile*64;
        #pragma unroll
        for (int rt = 0; rt < 4; rt++){
            int na = nb + rt*16 + l15;
            const float* xp = x + (size_t)min(na, NN-1)*64;
            short8 a[2];
            #pragma unroll
            for (int ks = 0; ks < 2; ks++){
                float xv[8];
                *(float4*)&xv[0] = *(const float4*)(xp + ks*32 + g*8);
                *(float4*)&xv[4] = *(const float4*)(xp + ks*32 + g*8 + 4);
                short8 av;
                #pragma unroll
                for (int j = 0; j < 8; j++) av[j] = (short)f2bf(xv[j]);
                a[ks] = av;
            }
            f32x4 acc0 = {0.f,0.f,0.f,0.f}, acc1 = {0.f,0.f,0.f,0.f};
            acc0 = __builtin_amdgcn_mfma_f32_16x16x32_bf16(a[0], bw[0][0], acc0, 0, 0, 0);
            acc0 = __builtin_amdgcn_mfma_f32_16x16x32_bf16(a[1], bw[0][1], acc0, 0, 0, 0);
            acc1 = __builtin_amdgcn_mfma_f32_16x16x32_bf16(a[0], bw[1][0], acc1, 0, 0, 0);
            acc1 = __builtin_amdgcn_mfma_f32_16x16x32_bf16(a[1], bw[1][1], acc1, 0, 0, 0);
            #pragma unroll
            for (int r = 0; r < 4; r++){
                int node = nb + rt*16 + g*4 + r;
                if (node < NN){
                    xw_h[(size_t)node*128 + wv*32 + l15]      = f2bf(acc0[r]);
                    xw_h[(size_t)node*128 + wv*32 + 16 + l15] = f2bf(acc1[r]);
                }
            }
            float ps[4], pd[4];
            #pragma unroll
            for (int r = 0; r < 4; r++){
                ps[r] = acc0[r]*attv_s[0] + acc1[r]*attv_s[1];
                pd[r] = acc0[r]*attv_d[0] + acc1[r]*attv_d[1];
            }
            #pragma unroll
            for (int d = 1; d < 16; d <<= 1){
                #pragma unroll
                for (int r = 0; r < 4; r++){
                    ps[r] += __shfl_xor(ps[r], d);
                    pd[r] += __shfl_xor(pd[r], d);
                }
            }
            if (l15 == 0){
                #pragma unroll
                for (int r = 0; r < 4; r++){
                    int node = nb + rt*16 + g*4 + r;
                    if (node < NN){
                        a_src[node*4 + wv] = ps[r];
                        a_dst[node*4 + wv] = pd[r];
                    }
                }
            }
        }
    }
}

// ---- GAT aggregation: single-pass softmax-gather, chunked 1-exp/edge/wave ----
__global__ __launch_bounds__(256) void k_gat(const int* __restrict__ rp,
        const int* __restrict__ col, const float* __restrict__ a_src,
        const float* __restrict__ a_dst, const uint* __restrict__ xw_u,
        const float* __restrict__ gb,
        const float* __restrict__ g1, const float* __restrict__ b1,
        const float* __restrict__ m1, const float* __restrict__ v1,
        ushort* __restrict__ h1_h){
    int gw = (blockIdx.x*256 + threadIdx.x) >> 6;
    int nwaves = (gridDim.x*256) >> 6;
    int lane = threadIdx.x & 63;
    int h4 = lane & 3;      // head for weight computation (lane = e4*4 + h4)
    int e4 = lane >> 2;     // edge slot 0..15
    int hh = lane >> 4;     // head for channels (lane owns ch 2*lane, 2*lane+1)
    int o0 = 2*lane, o1 = o0 + 1;
    float gb0 = gb[o0], gb1 = gb[o1];
    float sc0 = g1[o0]*rsqrtf(v1[o0]+1e-5f), sh0 = b1[o0] - m1[o0]*sc0;
    float sc1 = g1[o1]*rsqrtf(v1[o1]+1e-5f), sh1 = b1[o1] - m1[o1]*sc1;

    for (int n = gw; n < NN; n += nwaves){
        int r0 = rp[n], deg = rp[n+1] - r0;
        float adh4 = a_dst[n*4 + h4];
        float wself = __expf(leakyf(a_src[n*4 + hh] + a_dst[n*4 + hh]));
        uint v = xw_u[(size_t)n*64 + lane];
        float s  = wself;
        float ax = bflo(v)*wself, ay = bfhi(v)*wself;
        for (int base = 0; base < deg; base += 16){
            int cnt = min(deg - base, 16);
            // lane (e4,h4) computes weight for edge base+e4, head h4 (1 exp/edge/wave)
            float wgt_l = 0.f;
            if (e4 < cnt){
                int sx = col[r0 + base + e4];
                wgt_l = __expf(leakyf(a_src[sx*4 + h4] + adh4));
            }
            // gather: address path is direct uniform col load; alpha via data-path shfl
            for (int e = 0; e < cnt; e++){
                int sidx = col[r0 + base + e];
                float al = __shfl(wgt_l, e*4 + hh);
                uint vv = xw_u[(size_t)sidx*64 + lane];
                s  += al;
                ax += al*bflo(vv); ay += al*bfhi(vv);
            }
        }
        float Sinv = 1.f/(s + 1e-16f);
        ax = ax*Sinv + gb0; ay = ay*Sinv + gb1;
        ax = eluf(ax)*sc0 + sh0;
        ay = eluf(ay)*sc1 + sh1;
        *(uint*)(h1_h + (size_t)n*128 + o0) = pack2(ax, ay);
    }
}

// ---- SAGE gather-mean ----
__global__ __launch_bounds__(256) void k_mean(const int* __restrict__ rp,
        const int* __restrict__ col, const uint* __restrict__ h1_u,
        uint* __restrict__ mean_u){
    int gw = (blockIdx.x*256 + threadIdx.x) >> 6;
    int nwaves = (gridDim.x*256) >> 6;
    int lane = threadIdx.x & 63;
    for (int n = gw; n < NN; n += nwaves){
        int r0 = rp[n], deg = rp[n+1] - r0;
        float ax = 0.f, ay = 0.f;
        #pragma unroll 4
        for (int i = 0; i < deg; i++){
            uint v = h1_u[(size_t)col[r0+i]*64 + lane];
            ax += bflo(v); ay += bfhi(v);
        }
        float inv = deg > 0 ? 1.f/(float)deg : 0.f;
        mean_u[(size_t)n*64 + lane] = pack2(ax*inv, ay*inv);
    }
}

// ---- SAGE + BN2 + GCN-hw via MFMA ----
#define STILE 938
__global__ __launch_bounds__(256) void k_sage_mfma(
        const uint* __restrict__ mean_u, const uint* __restrict__ h1_u,
        const uint* __restrict__ wcat_u, const float* __restrict__ bl,
        const uint* __restrict__ gcb_u,
        const float* __restrict__ g2, const float* __restrict__ b2,
        const float* __restrict__ m2, const float* __restrict__ v2,
        ushort* __restrict__ hw_h)
{
    __shared__ ushort h2_s[64][72];
    int t = threadIdx.x;
    int w = t >> 6, lane = t & 63;
    int l15 = lane & 15, g = lane >> 4;
    int olane = w*16 + l15;

    short8 bw[8];
    #pragma unroll
    for (int ks = 0; ks < 8; ks++)
        bw[ks] = ld8(wcat_u + (size_t)olane*128 + ks*16 + g*4);
    short8 bg[2][2];
    #pragma unroll
    for (int ct = 0; ct < 2; ct++)
        #pragma unroll
        for (int ks = 0; ks < 2; ks++)
            bg[ct][ks] = ld8(gcb_u + (size_t)(ct*16 + l15)*32 + ks*16 + g*4);

    float blv = bl[olane];
    float scv = g2[olane]*rsqrtf(v2[olane]+1e-5f);
    float shv = b2[olane] - m2[olane]*scv;

    for (int tile = blockIdx.x; tile < STILE; tile += gridDim.x){
        int nb = tile*64;
        __syncthreads();
        #pragma unroll
        for (int rt = 0; rt < 4; rt++){
            f32x4 acc = {0.f, 0.f, 0.f, 0.f};
            size_t node = (size_t)(nb + rt*16 + l15);
            const uint* am = mean_u + node*64 + g*4;
            const uint* as = h1_u  + node*64 + g*4;
            #pragma unroll
            for (int ks = 0; ks < 4; ks++)
                acc = __builtin_amdgcn_mfma_f32_16x16x32_bf16(ld8(am + ks*16), bw[ks], acc, 0, 0, 0);
            #pragma unroll
            for (int ks = 0; ks < 4; ks++)
                acc = __builtin_amdgcn_mfma_f32_16x16x32_bf16(ld8(as + ks*16), bw[4+ks], acc, 0, 0, 0);
            #pragma unroll
            for (int r = 0; r < 4; r++){
                int row = rt*16 + g*4 + r;
                h2_s[row][olane] = f2bf(eluf(acc[r] + blv)*scv + shv);
            }
        }
        __syncthreads();
        short8 a2[2];
        #pragma unroll
        for (int ks = 0; ks < 2; ks++)
            a2[ks] = *(const short8*)&h2_s[w*16 + l15][ks*32 + g*8];
        #pragma unroll
        for (int ct = 0; ct < 2; ct++){
            f32x4 acc2 = {0.f, 0.f, 0.f, 0.f};
            #pragma unroll
            for (int ks = 0; ks < 2; ks++)
                acc2 = __builtin_amdgcn_mfma_f32_16x16x32_bf16(a2[ks], bg[ct][ks], acc2, 0, 0, 0);
            #pragma unroll
            for (int r = 0; r < 4; r++){
                int row = nb + w*16 + g*4 + r;
                if (row < NN) hw_h[(size_t)row*32 + ct*16 + l15] = f2bf(acc2[r]);
            }
        }
    }
}

// ---- GCN aggregation + ELU + BN3 ----
__global__ __launch_bounds__(256) void k_gcn(const int* __restrict__ rp,
        const int* __restrict__ col, const uint* __restrict__ hw_u,
        const float* __restrict__ dinv, const float* __restrict__ gb,
        const float* __restrict__ g3, const float* __restrict__ b3,
        const float* __restrict__ m3, const float* __restrict__ v3,
        float* __restrict__ out){
    int t = threadIdx.x;
    int n = blockIdx.x*4 + (t >> 6);
    int lane = t & 63, u = lane & 15, part = lane >> 4;
    int r0 = rp[n], deg = rp[n+1] - r0;
    float dn = dinv[n];
    float ax = 0.f, ay = 0.f;
    for (int i = part; i < deg; i += 4){
        int s = col[r0+i];
        float dv = dinv[s];
        uint hv = hw_u[(size_t)s*16 + u];
        ax += dv*bflo(hv); ay += dv*bfhi(hv);
    }
    ax += __shfl_xor(ax, 16); ay += __shfl_xor(ay, 16);
    ax += __shfl_xor(ax, 32); ay += __shfl_xor(ay, 32);
    if (part == 0){
        uint sv = hw_u[(size_t)n*16 + u];
        float tx = ax*dn + dn*dn*bflo(sv);
        float ty = ay*dn + dn*dn*bfhi(sv);
        int o0 = 2*u, o1 = o0 + 1;
        tx += gb[o0]; ty += gb[o1];
        tx = eluf(tx); ty = eluf(ty);
        tx = (tx - m3[o0]) * rsqrtf(v3[o0] + 1e-5f) * g3[o0] + b3[o0];
        ty = (ty - m3[o1]) * rsqrtf(v3[o1] + 1e-5f) * g3[o1] + b3[o1];
        *(float2*)(out + (size_t)n*32 + o0) = make_float2(tx, ty);
    }
}

extern "C" void kernel_launch(void* const* d_in, const int* in_sizes, int n_in,
                              void* d_out, int out_size, void* d_ws, size_t ws_size,
                              hipStream_t stream)
{
    const float* x     = (const float*)d_in[0];
    const int*   ei    = (const int*)d_in[1];
    const float* gat_w = (const float*)d_in[2];
    const float* att_s = (const float*)d_in[3];
    const float* att_d = (const float*)d_in[4];
    const float* gat_b = (const float*)d_in[5];
    const float* bn1g = (const float*)d_in[6],  *bn1b = (const float*)d_in[7];
    const float* bn1m = (const float*)d_in[8],  *bn1v = (const float*)d_in[9];
    const float* sage_wl = (const float*)d_in[10];
    const float* sage_bl = (const float*)d_in[11];
    const float* sage_wr = (const float*)d_in[12];
    const float* bn2g = (const float*)d_in[13], *bn2b = (const float*)d_in[14];
    const float* bn2m = (const float*)d_in[15], *bn2v = (const float*)d_in[16];
    const float* gcn_w = (const float*)d_in[17];
    const float* gcn_b = (const float*)d_in[18];
    const float* bn3g = (const float*)d_in[19], *bn3b = (const float*)d_in[20];
    const float* bn3m = (const float*)d_in[21], *bn3v = (const float*)d_in[22];

    const int* src  = ei;
    const int* dstp = ei + EE;

    char* W = (char*)d_ws;
    ushort* xw_h   = (ushort*)W;                       // N*128 bf16
    ushort* h1_h   = xw_h + (size_t)NN*128;            // N*128 bf16
    ushort* mean_h = h1_h + (size_t)NN*128;            // N*128 bf16
    ushort* hw_h   = mean_h + (size_t)NN*128;          // N*32 bf16
    float* a_s  = (float*)(hw_h + (size_t)NN*32 + 8192); // slack for OOB tile reads
    float* a_d  = a_s + (size_t)NN*4;
    float* dinv = a_d + (size_t)NN*4;
    int* row_ptr = (int*)(dinv + NN);                  // N+1
    int* col     = row_ptr + (NN+1);                   // E
    ushort* wcat_h = (ushort*)(col + EE);              // 64*256 bf16
    ushort* gcb_h  = wcat_h + 16384;                   // 32*64 bf16
    int* bhist  = (int*)(gcb_h + 2048);                // NBK
    int* bstart = bhist + NBK;                         // NBK+1
    int* bcur   = bstart + NBK + 1;                    // NBK
    char* p2 = (char*)(bcur + NBK);
    p2 = (char*)(((uintptr_t)p2 + 15) & ~(uintptr_t)15);
    int* pairs = (int*)p2;                             // E packed (4.8 MB)

    const uint* xw_u   = (const uint*)xw_h;
    const uint* h1_u   = (const uint*)h1_h;
    uint* mean_u = (uint*)mean_h;
    uint* hw_u   = (uint*)hw_h;
    const uint* wcat_u = (const uint*)wcat_h;
    const uint* gcb_u  = (const uint*)gcb_h;
    float* out = (float*)d_out;

    hipMemsetAsync(bhist, 0, NBK*sizeof(int), stream);
    k_bcount<<<256, 256, 0, stream>>>(dstp, bhist);
    k_prep<<<65, 256, 0, stream>>>(bhist, bstart, bcur, sage_wl, sage_wr, gcn_w,
                                   wcat_h, gcb_h);
    k_binsort<<<256, 256, 0, stream>>>(src, dstp, bcur, pairs);
    k_csr_local<<<NBK, 256, 0, stream>>>(bstart, pairs, row_ptr, col, dinv);

    k_xw_mfma<<<XTILE, 256, 0, stream>>>(x, gat_w, att_s, att_d, xw_h, a_s, a_d);
    k_gat<<<2048, 256, 0, stream>>>(row_ptr, col, a_s, a_d, xw_u, gat_b,
                                    bn1g, bn1b, bn1m, bn1v, h1_h);
    k_mean<<<2048, 256, 0, stream>>>(row_ptr, col, h1_u, mean_u);
    k_sage_mfma<<<STILE, 256, 0, stream>>>(mean_u, h1_u, wcat_u, sage_bl, gcb_u,
                                           bn2g, bn2b, bn2m, bn2v, hw_h);
    k_gcn<<<NN/4, 256, 0, stream>>>(row_ptr, col, hw_u, dinv, gcn_b,
                                    bn3g, bn3b, bn3m, bn3v, out);
}

// Round 17
// 253.649 us; speedup vs baseline: 1.2573x; 1.2573x over previous
//
#include <hip/hip_runtime.h>

#define NN 60000
#define EE 1200000
#define NBK 938          // ceil(60000/64) buckets of 64 nodes
#define CH  4096         // edges per block-chunk in k_binsort

typedef __attribute__((ext_vector_type(8))) short short8;
typedef __attribute__((ext_vector_type(4))) float f32x4;

__device__ __forceinline__ float leakyf(float x){ return x >= 0.f ? x : 0.2f*x; }
__device__ __forceinline__ float eluf(float x){ return x > 0.f ? x : expm1f(x); }

__device__ __forceinline__ float bflo(uint v){ union{uint i;float f;}c; c.i = v<<16; return c.f; }
__device__ __forceinline__ float bfhi(uint v){ union{uint i;float f;}c; c.i = v & 0xffff0000u; return c.f; }
__device__ __forceinline__ ushort f2bf(float f){ union{float f;uint i;}c; c.f=f;
    uint r = c.i + 0x7fffu + ((c.i>>16)&1u); return (ushort)(r>>16); }
__device__ __forceinline__ uint pack2(float a, float b){ return (uint)f2bf(a) | ((uint)f2bf(b)<<16); }
__device__ __forceinline__ short8 ld8(const uint* p){
    union{ uint4 u; short8 s; } c; c.u = *(const uint4*)p; return c.s; }

// ---- bucket histogram (938 counters, LDS-aggregated) ----
__global__ __launch_bounds__(256) void k_bcount(const int* __restrict__ dst,
                                                int* __restrict__ bhist){
    __shared__ int lh[NBK];
    int t = threadIdx.x;
    for (int j = t; j < NBK; j += 256) lh[j] = 0;
    __syncthreads();
    for (int e = blockIdx.x*256 + t; e < EE; e += gridDim.x*256)
        atomicAdd(&lh[dst[e] >> 6], 1);
    __syncthreads();
    for (int j = t; j < NBK; j += 256){
        int v = lh[j];
        if (v) atomicAdd(&bhist[j], v);
    }
}

// ---- block 0: scan bhist -> bstart/bcur ; blocks 1..64: weight prep ----
__global__ __launch_bounds__(256) void k_prep(const int* __restrict__ bhist,
        int* __restrict__ bstart, int* __restrict__ bcur,
        const float* __restrict__ wl, const float* __restrict__ wr,
        const float* __restrict__ gcw,
        ushort* __restrict__ wcat, ushort* __restrict__ gcb){
    int blk = blockIdx.x, t = threadIdx.x;
    if (blk == 0){
        __shared__ int stmp[256];
        int vals[4], s4 = 0;
        #pragma unroll
        for (int k = 0; k < 4; k++){
            int idx = t*4 + k;
            vals[k] = (idx < NBK) ? bhist[idx] : 0;
            s4 += vals[k];
        }
        stmp[t] = s4; __syncthreads();
        for (int off = 1; off < 256; off <<= 1){
            int o = (t >= off) ? stmp[t-off] : 0;
            __syncthreads();
            stmp[t] += o;
            __syncthreads();
        }
        int ex = stmp[t] - s4;
        #pragma unroll
        for (int k = 0; k < 4; k++){
            int idx = t*4 + k;
            if (idx < NBK){ bstart[idx] = ex; bcur[idx] = ex; ex += vals[k]; }
        }
        if (t == 0) bstart[NBK] = EE;
    } else {
        int g = (blk-1)*256 + t;
        if (g < 16384){
            int o = g >> 8, k = g & 255;
            float v = (k < 128) ? wl[o*128 + k] : wr[o*128 + (k-128)];
            wcat[g] = f2bf(v);
        }
        if (g < 2048) gcb[g] = f2bf(gcw[g]);
    }
}

// ---- bucket-sort edges into packed pairs[] ((src<<6)|dstlocal) ----
__global__ __launch_bounds__(256) void k_binsort(const int* __restrict__ src,
        const int* __restrict__ dst, int* __restrict__ bcur,
        int* __restrict__ pairs){
    __shared__ int hist[NBK];
    __shared__ int loff[NBK];
    __shared__ int rcur[NBK];
    __shared__ int gbase[NBK];
    __shared__ int2 buf2[CH];
    __shared__ int stmp[256];
    int t = threadIdx.x;
    for (int e0 = blockIdx.x*CH; e0 < EE; e0 += gridDim.x*CH){
        int cnt = min(CH, EE - e0);
        for (int j = t; j < NBK; j += 256){ hist[j] = 0; rcur[j] = 0; }
        __syncthreads();
        int pk[16], bb[16];
        #pragma unroll
        for (int k = 0; k < 16; k++){
            int j = t + k*256;
            bool ok = j < cnt;
            int s = 0, d = 0;
            if (ok){ s = src[e0+j]; d = dst[e0+j]; atomicAdd(&hist[d >> 6], 1); }
            pk[k] = (s << 6) | (d & 63);
            bb[k] = ok ? (d >> 6) : -1;
        }
        __syncthreads();
        int b0 = t*4, ssum = 0, hv[4];
        #pragma unroll
        for (int k2 = 0; k2 < 4; k2++){
            int idx = b0 + k2;
            hv[k2] = (idx < NBK) ? hist[idx] : 0;
            ssum += hv[k2];
        }
        stmp[t] = ssum; __syncthreads();
        for (int off = 1; off < 256; off <<= 1){
            int o = (t >= off) ? stmp[t-off] : 0;
            __syncthreads();
            stmp[t] += o;
            __syncthreads();
        }
        int excl = stmp[t] - ssum;
        #pragma unroll
        for (int k2 = 0; k2 < 4; k2++){
            int idx = b0 + k2;
            if (idx < NBK){ loff[idx] = excl; excl += hv[k2]; }
        }
        __syncthreads();
        for (int j = t; j < NBK; j += 256){
            int h = hist[j];
            if (h) gbase[j] = atomicAdd(&bcur[j], h);
        }
        __syncthreads();
        #pragma unroll
        for (int k = 0; k < 16; k++){
            int b = bb[k];
            if (b >= 0){
                int lpos = loff[b] + atomicAdd(&rcur[b], 1);
                buf2[lpos] = make_int2(pk[k], b);
            }
        }
        __syncthreads();
        for (int j = t; j < cnt; j += 256){
            int2 pr = buf2[j];
            pairs[gbase[pr.y] + (j - loff[pr.y])] = pr.x;
        }
        __syncthreads();
    }
}

// ---- local CSR finalize: counts+scan+rp+dinv+col ----
__global__ __launch_bounds__(256) void k_csr_local(const int* __restrict__ bstart,
        const int* __restrict__ pairs, int* __restrict__ rp,
        int* __restrict__ col, float* __restrict__ dinv){
    __shared__ int cnt64[64];
    int b = blockIdx.x, t = threadIdx.x;
    int nb0 = b*64;
    int base = bstart[b];
    int bsz = bstart[b+1] - base;
    if (t < 64) cnt64[t] = 0;
    __syncthreads();
    for (int i = t; i < bsz; i += 256)
        atomicAdd(&cnt64[pairs[base+i] & 63], 1);
    __syncthreads();
    if (t < 64){
        int v = cnt64[t];
        int inc = v;
        #pragma unroll
        for (int d = 1; d < 64; d <<= 1){
            int o = __shfl_up(inc, d);
            if (t >= d) inc += o;
        }
        int ex = inc - v;
        int node = nb0 + t;
        if (node < NN){
            rp[node] = base + ex;
            dinv[node] = rsqrtf((float)(v + 1));
        }
        cnt64[t] = ex;
    }
    __syncthreads();
    for (int i = t; i < bsz; i += 256){
        int pv = pairs[base + i];
        int lpos = atomicAdd(&cnt64[pv & 63], 1);
        col[base + lpos] = pv >> 6;
    }
    if (b == 0 && t == 0) rp[NN] = EE;
}

// ---- GAT linear via MFMA ----
#define XTILE 938
__global__ __launch_bounds__(256) void k_xw_mfma(const float* __restrict__ x,
        const float* __restrict__ w, const float* __restrict__ att_s,
        const float* __restrict__ att_d, ushort* __restrict__ xw_h,
        float* __restrict__ a_src, float* __restrict__ a_dst){
    int t = threadIdx.x;
    int wv = t >> 6, lane = t & 63;
    int l15 = lane & 15, g = lane >> 4;
    short8 bw[2][2];
    float attv_s[2], attv_d[2];
    #pragma unroll
    for (int ct = 0; ct < 2; ct++){
        int colo = wv*32 + ct*16 + l15;
        attv_s[ct] = att_s[colo];
        attv_d[ct] = att_d[colo];
        #pragma unroll
        for (int ks = 0; ks < 2; ks++){
            const float* wp = w + colo*64 + ks*32 + g*8;
            short8 b;
            #pragma unroll
            for (int j = 0; j < 8; j++) b[j] = (short)f2bf(wp[j]);
            bw[ct][ks] = b;
        }
    }
    for (int tile = blockIdx.x; tile < XTILE; tile += gridDim.x){
        int nb = tile*64;
        #pragma unroll
        for (int rt = 0; rt < 4; rt++){
            int na = nb + rt*16 + l15;
            const float* xp = x + (size_t)min(na, NN-1)*64;
            short8 a[2];
            #pragma unroll
            for (int ks = 0; ks < 2; ks++){
                float xv[8];
                *(float4*)&xv[0] = *(const float4*)(xp + ks*32 + g*8);
                *(float4*)&xv[4] = *(const float4*)(xp + ks*32 + g*8 + 4);
                short8 av;
                #pragma unroll
                for (int j = 0; j < 8; j++) av[j] = (short)f2bf(xv[j]);
                a[ks] = av;
            }
            f32x4 acc0 = {0.f,0.f,0.f,0.f}, acc1 = {0.f,0.f,0.f,0.f};
            acc0 = __builtin_amdgcn_mfma_f32_16x16x32_bf16(a[0], bw[0][0], acc0, 0, 0, 0);
            acc0 = __builtin_amdgcn_mfma_f32_16x16x32_bf16(a[1], bw[0][1], acc0, 0, 0, 0);
            acc1 = __builtin_amdgcn_mfma_f32_16x16x32_bf16(a[0], bw[1][0], acc1, 0, 0, 0);
            acc1 = __builtin_amdgcn_mfma_f32_16x16x32_bf16(a[1], bw[1][1], acc1, 0, 0, 0);
            #pragma unroll
            for (int r = 0; r < 4; r++){
                int node = nb + rt*16 + g*4 + r;
                if (node < NN){
                    xw_h[(size_t)node*128 + wv*32 + l15]      = f2bf(acc0[r]);
                    xw_h[(size_t)node*128 + wv*32 + 16 + l15] = f2bf(acc1[r]);
                }
            }
            float ps[4], pd[4];
            #pragma unroll
            for (int r = 0; r < 4; r++){
                ps[r] = acc0[r]*attv_s[0] + acc1[r]*attv_s[1];
                pd[r] = acc0[r]*attv_d[0] + acc1[r]*attv_d[1];
            }
            #pragma unroll
            for (int d = 1; d < 16; d <<= 1){
                #pragma unroll
                for (int r = 0; r < 4; r++){
                    ps[r] += __shfl_xor(ps[r], d);
                    pd[r] += __shfl_xor(pd[r], d);
                }
            }
            if (l15 == 0){
                #pragma unroll
                for (int r = 0; r < 4; r++){
                    int node = nb + rt*16 + g*4 + r;
                    if (node < NN){
                        a_src[node*4 + wv] = ps[r];
                        a_dst[node*4 + wv] = pd[r];
                    }
                }
            }
        }
    }
}

// ---- GAT aggregation: fused single-pass softmax-gather (no max-subtraction) ----
__global__ __launch_bounds__(256) void k_gat(const int* __restrict__ rp,
        const int* __restrict__ col, const float* __restrict__ a_src,
        const float* __restrict__ a_dst, const uint* __restrict__ xw_u,
        const float* __restrict__ gb,
        const float* __restrict__ g1, const float* __restrict__ b1,
        const float* __restrict__ m1, const float* __restrict__ v1,
        ushort* __restrict__ h1_h){
    int gw = (blockIdx.x*256 + threadIdx.x) >> 6;
    int nwaves = (gridDim.x*256) >> 6;
    int lane = threadIdx.x & 63;
    int hh = lane >> 4;
    int o0 = 2*lane, o1 = o0 + 1;
    float gb0 = gb[o0], gb1 = gb[o1];
    float sc0 = g1[o0]*rsqrtf(v1[o0]+1e-5f), sh0 = b1[o0] - m1[o0]*sc0;
    float sc1 = g1[o1]*rsqrtf(v1[o1]+1e-5f), sh1 = b1[o1] - m1[o1]*sc1;

    for (int n = gw; n < NN; n += nwaves){
        int r0 = rp[n], deg = rp[n+1] - r0;
        float adh = a_dst[n*4 + hh];
        float wself = __expf(leakyf(a_src[n*4 + hh] + adh));
        uint v = xw_u[(size_t)n*64 + lane];
        float s  = wself;
        float ax = bflo(v)*wself, ay = bfhi(v)*wself;
        #pragma unroll 4
        for (int i = 0; i < deg; i++){
            int sidx = col[r0+i];
            float wgt = __expf(leakyf(a_src[sidx*4 + hh] + adh));
            uint vv = xw_u[(size_t)sidx*64 + lane];
            s  += wgt;
            ax += wgt*bflo(vv); ay += wgt*bfhi(vv);
        }
        float Sinv = 1.f/(s + 1e-16f);
        ax = ax*Sinv + gb0; ay = ay*Sinv + gb1;
        ax = eluf(ax)*sc0 + sh0;
        ay = eluf(ay)*sc1 + sh1;
        *(uint*)(h1_h + (size_t)n*128 + o0) = pack2(ax, ay);
    }
}

// ---- SAGE gather-mean ----
__global__ __launch_bounds__(256) void k_mean(const int* __restrict__ rp,
        const int* __restrict__ col, const uint* __restrict__ h1_u,
        uint* __restrict__ mean_u){
    int gw = (blockIdx.x*256 + threadIdx.x) >> 6;
    int nwaves = (gridDim.x*256) >> 6;
    int lane = threadIdx.x & 63;
    for (int n = gw; n < NN; n += nwaves){
        int r0 = rp[n], deg = rp[n+1] - r0;
        float ax = 0.f, ay = 0.f;
        #pragma unroll 4
        for (int i = 0; i < deg; i++){
            uint v = h1_u[(size_t)col[r0+i]*64 + lane];
            ax += bflo(v); ay += bfhi(v);
        }
        float inv = deg > 0 ? 1.f/(float)deg : 0.f;
        mean_u[(size_t)n*64 + lane] = pack2(ax*inv, ay*inv);
    }
}

// ---- SAGE + BN2 + GCN-hw via MFMA ----
#define STILE 938
__global__ __launch_bounds__(256) void k_sage_mfma(
        const uint* __restrict__ mean_u, const uint* __restrict__ h1_u,
        const uint* __restrict__ wcat_u, const float* __restrict__ bl,
        const uint* __restrict__ gcb_u,
        const float* __restrict__ g2, const float* __restrict__ b2,
        const float* __restrict__ m2, const float* __restrict__ v2,
        ushort* __restrict__ hw_h)
{
    __shared__ ushort h2_s[64][72];
    int t = threadIdx.x;
    int w = t >> 6, lane = t & 63;
    int l15 = lane & 15, g = lane >> 4;
    int olane = w*16 + l15;

    short8 bw[8];
    #pragma unroll
    for (int ks = 0; ks < 8; ks++)
        bw[ks] = ld8(wcat_u + (size_t)olane*128 + ks*16 + g*4);
    short8 bg[2][2];
    #pragma unroll
    for (int ct = 0; ct < 2; ct++)
        #pragma unroll
        for (int ks = 0; ks < 2; ks++)
            bg[ct][ks] = ld8(gcb_u + (size_t)(ct*16 + l15)*32 + ks*16 + g*4);

    float blv = bl[olane];
    float scv = g2[olane]*rsqrtf(v2[olane]+1e-5f);
    float shv = b2[olane] - m2[olane]*scv;

    for (int tile = blockIdx.x; tile < STILE; tile += gridDim.x){
        int nb = tile*64;
        __syncthreads();
        #pragma unroll
        for (int rt = 0; rt < 4; rt++){
            f32x4 acc = {0.f, 0.f, 0.f, 0.f};
            size_t node = (size_t)(nb + rt*16 + l15);
            const uint* am = mean_u + node*64 + g*4;
            const uint* as = h1_u  + node*64 + g*4;
            #pragma unroll
            for (int ks = 0; ks < 4; ks++)
                acc = __builtin_amdgcn_mfma_f32_16x16x32_bf16(ld8(am + ks*16), bw[ks], acc, 0, 0, 0);
            #pragma unroll
            for (int ks = 0; ks < 4; ks++)
                acc = __builtin_amdgcn_mfma_f32_16x16x32_bf16(ld8(as + ks*16), bw[4+ks], acc, 0, 0, 0);
            #pragma unroll
            for (int r = 0; r < 4; r++){
                int row = rt*16 + g*4 + r;
                h2_s[row][olane] = f2bf(eluf(acc[r] + blv)*scv + shv);
            }
        }
        __syncthreads();
        short8 a2[2];
        #pragma unroll
        for (int ks = 0; ks < 2; ks++)
            a2[ks] = *(const short8*)&h2_s[w*16 + l15][ks*32 + g*8];
        #pragma unroll
        for (int ct = 0; ct < 2; ct++){
            f32x4 acc2 = {0.f, 0.f, 0.f, 0.f};
            #pragma unroll
            for (int ks = 0; ks < 2; ks++)
                acc2 = __builtin_amdgcn_mfma_f32_16x16x32_bf16(a2[ks], bg[ct][ks], acc2, 0, 0, 0);
            #pragma unroll
            for (int r = 0; r < 4; r++){
                int row = nb + w*16 + g*4 + r;
                if (row < NN) hw_h[(size_t)row*32 + ct*16 + l15] = f2bf(acc2[r]);
            }
        }
    }
}

// ---- GCN aggregation + ELU + BN3 ----
__global__ __launch_bounds__(256) void k_gcn(const int* __restrict__ rp,
        const int* __restrict__ col, const uint* __restrict__ hw_u,
        const float* __restrict__ dinv, const float* __restrict__ gb,
        const float* __restrict__ g3, const float* __restrict__ b3,
        const float* __restrict__ m3, const float* __restrict__ v3,
        float* __restrict__ out){
    int t = threadIdx.x;
    int n = blockIdx.x*4 + (t >> 6);
    int lane = t & 63, u = lane & 15, part = lane >> 4;
    int r0 = rp[n], deg = rp[n+1] - r0;
    float dn = dinv[n];
    float ax = 0.f, ay = 0.f;
    for (int i = part; i < deg; i += 4){
        int s = col[r0+i];
        float dv = dinv[s];
        uint hv = hw_u[(size_t)s*16 + u];
        ax += dv*bflo(hv); ay += dv*bfhi(hv);
    }
    ax += __shfl_xor(ax, 16); ay += __shfl_xor(ay, 16);
    ax += __shfl_xor(ax, 32); ay += __shfl_xor(ay, 32);
    if (part == 0){
        uint sv = hw_u[(size_t)n*16 + u];
        float tx = ax*dn + dn*dn*bflo(sv);
        float ty = ay*dn + dn*dn*bfhi(sv);
        int o0 = 2*u, o1 = o0 + 1;
        tx += gb[o0]; ty += gb[o1];
        tx = eluf(tx); ty = eluf(ty);
        tx = (tx - m3[o0]) * rsqrtf(v3[o0] + 1e-5f) * g3[o0] + b3[o0];
        ty = (ty - m3[o1]) * rsqrtf(v3[o1] + 1e-5f) * g3[o1] + b3[o1];
        *(float2*)(out + (size_t)n*32 + o0) = make_float2(tx, ty);
    }
}

extern "C" void kernel_launch(void* const* d_in, const int* in_sizes, int n_in,
                              void* d_out, int out_size, void* d_ws, size_t ws_size,
                              hipStream_t stream)
{
    const float* x     = (const float*)d_in[0];
    const int*   ei    = (const int*)d_in[1];
    const float* gat_w = (const float*)d_in[2];
    const float* att_s = (const float*)d_in[3];
    const float* att_d = (const float*)d_in[4];
    const float* gat_b = (const float*)d_in[5];
    const float* bn1g = (const float*)d_in[6],  *bn1b = (const float*)d_in[7];
    const float* bn1m = (const float*)d_in[8],  *bn1v = (const float*)d_in[9];
    const float* sage_wl = (const float*)d_in[10];
    const float* sage_bl = (const float*)d_in[11];
    const float* sage_wr = (const float*)d_in[12];
    const float* bn2g = (const float*)d_in[13], *bn2b = (const float*)d_in[14];
    const float* bn2m = (const float*)d_in[15], *bn2v = (const float*)d_in[16];
    const float* gcn_w = (const float*)d_in[17];
    const float* gcn_b = (const float*)d_in[18];
    const float* bn3g = (const float*)d_in[19], *bn3b = (const float*)d_in[20];
    const float* bn3m = (const float*)d_in[21], *bn3v = (const float*)d_in[22];

    const int* src  = ei;
    const int* dstp = ei + EE;

    char* W = (char*)d_ws;
    ushort* xw_h   = (ushort*)W;                       // N*128 bf16
    ushort* h1_h   = xw_h + (size_t)NN*128;            // N*128 bf16
    ushort* mean_h = h1_h + (size_t)NN*128;            // N*128 bf16
    ushort* hw_h   = mean_h + (size_t)NN*128;          // N*32 bf16
    float* a_s  = (float*)(hw_h + (size_t)NN*32 + 8192); // slack for OOB tile reads
    float* a_d  = a_s + (size_t)NN*4;
    float* dinv = a_d + (size_t)NN*4;
    int* row_ptr = (int*)(dinv + NN);                  // N+1
    int* col     = row_ptr + (NN+1);                   // E
    ushort* wcat_h = (ushort*)(col + EE);              // 64*256 bf16
    ushort* gcb_h  = wcat_h + 16384;                   // 32*64 bf16
    int* bhist  = (int*)(gcb_h + 2048);                // NBK
    int* bstart = bhist + NBK;                         // NBK+1
    int* bcur   = bstart + NBK + 1;                    // NBK
    char* p2 = (char*)(bcur + NBK);
    p2 = (char*)(((uintptr_t)p2 + 15) & ~(uintptr_t)15);
    int* pairs = (int*)p2;                             // E packed (4.8 MB)

    const uint* xw_u   = (const uint*)xw_h;
    const uint* h1_u   = (const uint*)h1_h;
    uint* mean_u = (uint*)mean_h;
    uint* hw_u   = (uint*)hw_h;
    const uint* wcat_u = (const uint*)wcat_h;
    const uint* gcb_u  = (const uint*)gcb_h;
    float* out = (float*)d_out;

    hipMemsetAsync(bhist, 0, NBK*sizeof(int), stream);
    k_bcount<<<256, 256, 0, stream>>>(dstp, bhist);
    k_prep<<<65, 256, 0, stream>>>(bhist, bstart, bcur, sage_wl, sage_wr, gcn_w,
                                   wcat_h, gcb_h);
    k_binsort<<<256, 256, 0, stream>>>(src, dstp, bcur, pairs);
    k_csr_local<<<NBK, 256, 0, stream>>>(bstart, pairs, row_ptr, col, dinv);

    k_xw_mfma<<<XTILE, 256, 0, stream>>>(x, gat_w, att_s, att_d, xw_h, a_s, a_d);
    k_gat<<<2048, 256, 0, stream>>>(row_ptr, col, a_s, a_d, xw_u, gat_b,
                                    bn1g, bn1b, bn1m, bn1v, h1_h);
    k_mean<<<2048, 256, 0, stream>>>(row_ptr, col, h1_u, mean_u);
    k_sage_mfma<<<STILE, 256, 0, stream>>>(mean_u, h1_u, wcat_u, sage_bl, gcb_u,
                                           bn2g, bn2b, bn2m, bn2v, hw_h);
    k_gcn<<<NN/4, 256, 0, stream>>>(row_ptr, col, hw_u, dinv, gcn_b,
                                    bn3g, bn3b, bn3m, bn3v, out);
}